// Round 10
// baseline (630.458 us; speedup 1.0000x reference)
//
#include <hip/hip_runtime.h>
#include <hip/hip_bf16.h>
#include <stdint.h>

typedef __attribute__((ext_vector_type(8))) short bf16x8;
typedef __attribute__((ext_vector_type(4))) float f32x4;
typedef __attribute__((ext_vector_type(8))) unsigned short u16x8;

#define BM 256
#define BN 256
#define BKT 32
#define ABYTES (BM * BKT * 2)        // 16384
#define BBYTES (BN * BKT * 2)        // 16384
#define BUFBYTES (ABYTES + BBYTES)   // 32768
#define NBUF 4                       // 128 KB LDS ring, depth-2 prefetch

// ---- MXFP8 quant-dequant to bf16 (verified r1/r5-r8: absmax 0.03125) -------
__device__ __forceinline__ float mx_qd_elem(float x, int e) {
    float xs = ldexpf(x, -e);
    xs = fminf(448.f, fmaxf(-448.f, xs));
    float a = fabsf(xs);
    float r;
    if (a < 0.015625f) {                  // below 2^-6: e4m3 subnormal, quantum 2^-9
        r = ldexpf(rintf(ldexpf(a, 9)), -9);
    } else {                              // normal: quantum 2^(E-3)
        int E = (int)((__float_as_uint(a) >> 23) & 0xFF) - 127;
        r = ldexpf(rintf(ldexpf(a, 3 - E)), E - 3);
    }
    r = copysignf(r, xs);
    return ldexpf(r, e);
}

__global__ __launch_bounds__(256) void mx_quant_bf16(
    const float* __restrict__ in, uint16_t* __restrict__ out, int nblk) {
    int t = blockIdx.x * 256 + threadIdx.x;
    if (t >= nblk) return;
    const float4* p = (const float4*)(in + (size_t)t * 32);
    float v[32];
#pragma unroll
    for (int i = 0; i < 8; ++i) {
        float4 fv = p[i];
        v[4 * i + 0] = fv.x; v[4 * i + 1] = fv.y;
        v[4 * i + 2] = fv.z; v[4 * i + 3] = fv.w;
    }
    float amax = 0.f;
#pragma unroll
    for (int i = 0; i < 32; ++i) amax = fmaxf(amax, fabsf(v[i]));
    amax = fmaxf(amax, 1.17549435e-38f);
    int e = (int)((__float_as_uint(amax) >> 23) & 0xFF) - 127 - 8;

    unsigned short res[32];
#pragma unroll
    for (int i = 0; i < 32; ++i) {
        float d = mx_qd_elem(v[i], e);
        res[i] = (unsigned short)(__float_as_uint(d) >> 16);
    }
    u16x8* o = (u16x8*)(out + (size_t)t * 32);
#pragma unroll
    for (int j = 0; j < 4; ++j) {
        u16x8 pack;
#pragma unroll
        for (int i = 0; i < 8; ++i) pack[i] = res[8 * j + i];
        o[j] = pack;
    }
}

// ---- 256x256 depth-2 pipelined bf16 GEMM: C = A * B^T + bias ---------------
// 8 waves (2M x 4N), per-wave 128x64 (acc[8][4]); BK=32; 4-buf LDS ring;
// stage(t+2) during tile t; boundary wait COUNTED vmcnt(4) while prefetch in
// flight, vmcnt(0) only for the tail (r9 bug: vmcnt(4) was a no-op at
// t=nt-2, racing the last tile); counted lgkm chunks; slot-swizzle
// (slot ^= (row>>1)&3) -> 2-way-aliased banks = conflict-free (m136).
#define GLOAD(srcp, ldsoff)                                                     \
    __builtin_amdgcn_global_load_lds(                                           \
        (const __attribute__((address_space(1))) void*)(srcp),                  \
        (__attribute__((address_space(3))) void*)&lds[ldsoff], 16, 0, 0)

__global__ __launch_bounds__(512, 2) void gemm_d2_bf16(
    const uint16_t* __restrict__ A, const uint16_t* __restrict__ B,
    const float* __restrict__ bias, float* __restrict__ C,
    int Nrows, int K, int O) {
    __shared__ __align__(16) uint8_t lds[NBUF * BUFBYTES];   // 128 KB

    const int tid  = threadIdx.x;
    const int lane = tid & 63;
    const int w    = tid >> 6;
    const int f    = lane & 15, g = lane >> 4;
    const int wm   = w >> 2,    wn = w & 3;     // 2M x 4N

    // T1: bijective XCD swizzle (nwg = 1024, %8 == 0)
    const int nwg  = gridDim.x * gridDim.y;
    const int flat = blockIdx.y * gridDim.x + blockIdx.x;
    const int swz  = (flat & 7) * (nwg >> 3) + (flat >> 3);
    const int bx   = swz % gridDim.x, by = swz / gridDim.x;
    const int rowBase = by * BM, colBase = bx * BN;

    // staging: 16KB/matrix/tile; thread covers one 16B unit per GLOAD round.
    // linear LDS dest (rule 21 / m104: dest is wave-base + lane*16);
    // SOURCE col = (slot ^ ((row>>1)&3))*16  (involution, 16B-contiguous).
    const int srow = tid >> 2;                               // 0..127
    const int ssc  = ((tid & 3) ^ ((srow >> 1) & 3)) * 16;   // source byte col
    const size_t K2 = (size_t)K * 2;
    const uint8_t* gA0 = (const uint8_t*)A + (size_t)(rowBase + srow) * K2 + ssc;
    const uint8_t* gA1 = (const uint8_t*)A + (size_t)(rowBase + 128 + srow) * K2 + ssc;
    const uint8_t* gB0 = (const uint8_t*)B + (size_t)(colBase + srow) * K2 + ssc;
    const uint8_t* gB1 = (const uint8_t*)B + (size_t)(colBase + 128 + srow) * K2 + ssc;
    const int sld = tid * 16;
#define STAGE(t) do {                                                           \
        const int _buf = ((t) & 3) * BUFBYTES;                                  \
        const size_t _kb = (size_t)(t) * (BKT * 2);                             \
        GLOAD(gA0 + _kb, _buf + sld);                                           \
        GLOAD(gA1 + _kb, _buf + 8192 + sld);                                    \
        GLOAD(gB0 + _kb, _buf + ABYTES + sld);                                  \
        GLOAD(gB1 + _kb, _buf + ABYTES + 8192 + sld);                           \
    } while (0)

    // frag-read offsets: row r (64B), k-slot g -> r*64 + (g ^ ((r>>1)&3))*16
    // LDS(r,s) holds G(r, s^((r>>1)&3)); reading slot g^((r>>1)&3) gives G(r,g).
    int aoff[8], boff[4];
#pragma unroll
    for (int m = 0; m < 8; ++m) {
        int r = wm * 128 + m * 16 + f;
        aoff[m] = r * 64 + ((g ^ ((r >> 1) & 3)) * 16);
    }
#pragma unroll
    for (int n = 0; n < 4; ++n) {
        int r = wn * 64 + n * 16 + f;
        boff[n] = ABYTES + r * 64 + ((g ^ ((r >> 1) & 3)) * 16);
    }

    f32x4 acc[8][4];
#pragma unroll
    for (int m = 0; m < 8; ++m)
#pragma unroll
        for (int n = 0; n < 4; ++n)
#pragma unroll
            for (int j = 0; j < 4; ++j) acc[m][n][j] = 0.f;

    const int nt = K / BKT;   // 128

#define WAITL(N) do {                                                           \
        asm volatile("s_waitcnt lgkmcnt(" #N ")" ::: "memory");                 \
        __builtin_amdgcn_sched_barrier(0);                                      \
    } while (0)
#define MFMA_C(MB, AF, BF) do {                                                 \
        __builtin_amdgcn_s_setprio(1);                                          \
        _Pragma("unroll") for (int _m = 0; _m < 4; ++_m)                        \
        _Pragma("unroll") for (int _n = 0; _n < 4; ++_n)                        \
            acc[(MB) + _m][_n] = __builtin_amdgcn_mfma_f32_16x16x32_bf16(       \
                AF[_m], BF[_n], acc[(MB) + _m][_n], 0, 0, 0);                   \
        __builtin_amdgcn_s_setprio(0);                                          \
    } while (0)

    // prologue: stage tiles 0,1; publish tile 0 with tile 1 in flight
    STAGE(0);
    STAGE(1);
    asm volatile("s_waitcnt vmcnt(4)" ::: "memory");
    __builtin_amdgcn_sched_barrier(0);
    __builtin_amdgcn_s_barrier();
    __builtin_amdgcn_sched_barrier(0);

    for (int t = 0; t < nt; ++t) {
        const int bb = (t & 3) * BUFBYTES;
        const bool pf = (t + 2) < nt;
        bf16x8 bA[4], aLo[4], aHi[4];

        // c0 (8 reads): B + A m0-3
#pragma unroll
        for (int n = 0; n < 4; ++n) bA[n] = *(const bf16x8*)&lds[bb + boff[n]];
#pragma unroll
        for (int m = 0; m < 4; ++m) aLo[m] = *(const bf16x8*)&lds[bb + aoff[m]];
        // c1 (4 reads): A m4-7
#pragma unroll
        for (int m = 0; m < 4; ++m) aHi[m] = *(const bf16x8*)&lds[bb + aoff[4 + m]];
        if (pf) STAGE(t + 2);            // gload issue overlaps c0 drain
        WAITL(4);                        // c0 done (c1 outstanding)
        MFMA_C(0, aLo, bA);              // cluster 1; c1 drains under it
        WAITL(0);                        // c1 done
        MFMA_C(4, aHi, bA);              // cluster 2
        // boundary wait must retire stage(t+1):
        //   steady state (stage(t+2) in flight): vmcnt(4)
        //   tail (no stage(t+2) issued):         vmcnt(0)  [r9 fix]
        if (pf) asm volatile("s_waitcnt vmcnt(4)" ::: "memory");
        else    asm volatile("s_waitcnt vmcnt(0)" ::: "memory");
        __builtin_amdgcn_sched_barrier(0);
        __builtin_amdgcn_s_barrier();
        __builtin_amdgcn_sched_barrier(0);
    }
#undef STAGE
#undef WAITL
#undef MFMA_C

    // epilogue: C/D layout col=lane&15, row=(lane>>4)*4+j (r1/r5-r8 verified)
    const int qr = g * 4;
#pragma unroll
    for (int n = 0; n < 4; ++n) {
        int col = colBase + wn * 64 + n * 16 + f;
        float bv = bias[col];
#pragma unroll
        for (int m = 0; m < 8; ++m) {
            int r0 = rowBase + wm * 128 + m * 16 + qr;
#pragma unroll
            for (int j = 0; j < 4; ++j)
                C[(size_t)(r0 + j) * O + col] = acc[m][n][j] + bv;
        }
    }
}

extern "C" void kernel_launch(void* const* d_in, const int* in_sizes, int n_in,
                              void* d_out, int out_size, void* d_ws, size_t ws_size,
                              hipStream_t stream) {
    const float* x    = (const float*)d_in[0];
    const float* wgt  = (const float*)d_in[1];
    const float* bias = (const float*)d_in[2];
    float* out = (float*)d_out;

    const int D_OUT = in_sizes[2];             // 4096
    const int D_IN  = in_sizes[1] / D_OUT;     // 4096
    const int NROWS = in_sizes[0] / D_IN;      // 16384

    uint16_t* xq = (uint16_t*)d_ws;                     // 128 MB
    uint16_t* wq = xq + (size_t)NROWS * D_IN;           //  32 MB

    int nblkx = NROWS * (D_IN / 32);
    int nblkw = D_OUT * (D_IN / 32);
    mx_quant_bf16<<<dim3((nblkx + 255) / 256), dim3(256), 0, stream>>>(x, xq, nblkx);
    mx_quant_bf16<<<dim3((nblkw + 255) / 256), dim3(256), 0, stream>>>(wgt, wq, nblkw);

    dim3 grid(D_OUT / BN, NROWS / BM);   // (16, 64) = 1024 blocks
    gemm_d2_bf16<<<grid, dim3(512), 0, stream>>>(xq, wq, bias, out,
                                                 NROWS, D_IN, D_OUT);
}